// Round 10
// baseline (234.069 us; speedup 1.0000x reference)
//
#include <hip/hip_runtime.h>

// ---------------------------------------------------------------------------
// unit_gcn: out[n,o,t,v] = BN+ReLU of  sum_{s=0..24} Ws[s] @_c x[n,:,t,(v+s)%25]
//   Ws[0] = sum_i W[i,:,:,0];  Ws[s] = W[s-1,:,:,1]  (s>=1); bias cancels in BN.
// N=64, C=64, T=300, V=25, O=64.  x fp32 -> bf16 MFMA (16x16x32), fp32 accum.
// v7 (R10): R9 schedule, occupancy-fixed geometry: 256-thr blocks, 4 waves x
// (64 rows x 64 o), 256 flat rows/block, ~164 unified regs -> 3 blocks/CU
// (12 waves/CU, 3/SIMD even). Slab 300x144B zero-filled.
// ---------------------------------------------------------------------------

typedef short  s16x8 __attribute__((ext_vector_type(8)));
typedef float  f32x4 __attribute__((ext_vector_type(4)));

#define NTHR_   256
#define RPB_    256         // flat (t,v) rows per block
#define NBR_    30          // ceil(7500/256)
#define SLAB_   300         // slab rows (max t-span 12 x 25)
#define ASTR    144         // slab row stride bytes (64c*2B + 16 pad; 16B-aligned)
#define TSTR    260         // epilogue transpose stride (f32)

__device__ __forceinline__ unsigned short f2bf(float f) {
  unsigned u = __builtin_bit_cast(unsigned, f);
  return (unsigned short)((u + 0x7FFFu + ((u >> 16) & 1u)) >> 16);
}

// --- P0: pack Ws into MFMA B-fragment layout (s-major: q = s*2 + chunk) ----
// Wg entry idx = ((s*2+chunk)*4 + ni)*64 + lane ; 8 bf16 per entry:
//   elem j = Ws[s][ o = ni*16 + (lane&15) ][ c = chunk*32 + (lane>>4)*8 + j ]
__global__ void pack_w_kernel(const float* __restrict__ W, s16x8* __restrict__ Wg) {
  int idx = blockIdx.x * 256 + threadIdx.x;
  if (idx >= 12800) return;
  int lane  = idx & 63;
  int ni    = (idx >> 6) & 3;
  int chunk = (idx >> 8) & 1;
  int s     = idx >> 9;
  int o     = (ni << 4) + (lane & 15);
  int cbase = (chunk << 5) + ((lane >> 4) << 3);
  s16x8 h;
#pragma unroll
  for (int j = 0; j < 8; ++j) {
    int c = cbase + j;
    float val;
    if (s == 0) {
      val = 0.f;
      for (int i = 0; i < 24; ++i) val += W[((i * 64 + o) * 64 + c) * 2];
    } else {
      val = W[(((s - 1) * 64 + o) * 64 + c) * 2 + 1];
    }
    h[j] = (short)f2bf(val);
  }
  Wg[idx] = h;
}

// 4 MFMAs: acc[J][0..3] += SR x Q0..Q3   (J literal)
#define MF(J, Q0, Q1, Q2, Q3, SR)                                               \
  acc[J][0] = __builtin_amdgcn_mfma_f32_16x16x32_bf16(SR, Q0, acc[J][0], 0, 0, 0); \
  acc[J][1] = __builtin_amdgcn_mfma_f32_16x16x32_bf16(SR, Q1, acc[J][1], 0, 0, 0); \
  acc[J][2] = __builtin_amdgcn_mfma_f32_16x16x32_bf16(SR, Q2, acc[J][2], 0, 0, 0); \
  acc[J][3] = __builtin_amdgcn_mfma_f32_16x16x32_bf16(SR, Q3, acc[J][3], 0, 0, 0);

// advance row-tile J's shift state (period 25, same t-block)
#define ADV(J)                                                                  \
  { bool w_ = (u[J] == 24); u[J] = w_ ? 0 : u[J] + 1;                           \
    ao[J] += w_ ? -(24 * ASTR) : ASTR; }

// One shift-phase (8 substeps, 32 MFMA). On entry S0..S3 = chunk0 frags of
// this shift. Substep j consumes S_j, issues read for j+4 (chunk1, then next
// shift's chunk0). B-set reloaded with shift SN (= s+2) after last use.
#define PHASE(BA0, BA1, BA2, BA3, BA4, BA5, BA6, BA7, SN)                       \
  {                                                                             \
    const s16x8* wq_ = Wg + (SN) * 512;                                         \
    MF(0, BA0, BA1, BA2, BA3, S0) S0 = *(const s16x8*)(Ash + ao[0] + 64);       \
    MF(1, BA0, BA1, BA2, BA3, S1) S1 = *(const s16x8*)(Ash + ao[1] + 64);       \
    MF(2, BA0, BA1, BA2, BA3, S2) S2 = *(const s16x8*)(Ash + ao[2] + 64);       \
    MF(3, BA0, BA1, BA2, BA3, S3) S3 = *(const s16x8*)(Ash + ao[3] + 64);       \
    BA0 = wq_[lane];       BA1 = wq_[64 + lane];                                \
    BA2 = wq_[128 + lane]; BA3 = wq_[192 + lane];                               \
    ADV(0) MF(0, BA4, BA5, BA6, BA7, S0) S0 = *(const s16x8*)(Ash + ao[0]);     \
    ADV(1) MF(1, BA4, BA5, BA6, BA7, S1) S1 = *(const s16x8*)(Ash + ao[1]);     \
    ADV(2) MF(2, BA4, BA5, BA6, BA7, S2) S2 = *(const s16x8*)(Ash + ao[2]);     \
    ADV(3) MF(3, BA4, BA5, BA6, BA7, S3) S3 = *(const s16x8*)(Ash + ao[3]);     \
    BA4 = wq_[256 + lane]; BA5 = wq_[320 + lane];                               \
    BA6 = wq_[384 + lane]; BA7 = wq_[448 + lane];                               \
  }

// --- P1: main tap-GEMM -----------------------------------------------------
// grid (br=30, n=64), 256 thr = 4 waves; wave owns 64 rows x 64 o.
// Slab [300][64c] bf16 stride 144B (zero-filled beyond data), staged once.
__global__ __launch_bounds__(NTHR_) void tap_mm_kernel(
    const float* __restrict__ x, const s16x8* __restrict__ Wg,
    float* __restrict__ out, float* __restrict__ partials) {
  __shared__ __align__(16) char Ash[SLAB_ * ASTR];   // 43200B; epi T[16][260] f32
  __shared__ float red2[512];
  int br = blockIdx.x, n = blockIdx.y;
  int r0 = br * RPB_;
  int validR = min(RPB_, 7500 - r0);
  int t0g = r0 / 25;
  int tlast = (r0 + validR - 1) / 25;
  int slabRows = (tlast - t0g + 1) * 25;       // <= 300
  const float* xn = x + n * 480000;
  int xbase = t0g * 25;
  int tid = threadIdx.x;
  int wid = tid >> 6, lane = tid & 63;
  int l15 = lane & 15, lk = lane >> 4;

  // ---- B prologue: shifts 0 and 1, both chunks (global, L2-hot; issue first)
  s16x8 bfA0 = Wg[lane],       bfA1 = Wg[64 + lane];
  s16x8 bfA2 = Wg[128 + lane], bfA3 = Wg[192 + lane];
  s16x8 bfA4 = Wg[256 + lane], bfA5 = Wg[320 + lane];
  s16x8 bfA6 = Wg[384 + lane], bfA7 = Wg[448 + lane];
  s16x8 bfB0 = Wg[512 + lane], bfB1 = Wg[576 + lane];
  s16x8 bfB2 = Wg[640 + lane], bfB3 = Wg[704 + lane];
  s16x8 bfB4 = Wg[768 + lane], bfB5 = Wg[832 + lane];
  s16x8 bfB6 = Wg[896 + lane], bfB7 = Wg[960 + lane];

  // ---- stage slab: 2400 tasks {8 strided c-loads -> 16B ds_write}, zero-fill
#pragma unroll 5
  for (int it = 0; it < 10; ++it) {
    int id = tid + it * NTHR_;
    if (id < 2400) {
      int g = id / 300, pos = id - g * 300;    // g: 8-c group, pos: slab row
      bool vld = pos < slabRows;
      s16x8 h;
#pragma unroll
      for (int j = 0; j < 8; ++j) {
        float f = vld ? xn[((g << 3) + j) * 7500 + xbase + pos] : 0.f;
        h[j] = (short)f2bf(f);
      }
      *(s16x8*)(Ash + pos * ASTR + (g << 4)) = h;
    }
  }

  int u[4], ao[4];                      // ao = slabRow*ASTR + lk*16 (chunk0)
#pragma unroll
  for (int rt = 0; rt < 4; ++rt) {
    int gr = r0 + (wid << 6) + (rt << 4) + l15;   // A-side row this lane feeds
    int tL = gr / 25;
    u[rt]  = gr - tL * 25;                        // cycles with s, period 25
    ao[rt] = ((tL - t0g) * 25 + u[rt]) * ASTR + (lk << 4);
  }
  f32x4 acc[4][4];
#pragma unroll
  for (int rt = 0; rt < 4; ++rt)
#pragma unroll
    for (int ct = 0; ct < 4; ++ct) acc[rt][ct] = (f32x4){0.f, 0.f, 0.f, 0.f};

  __syncthreads();

  // ---- A-ring prologue: chunk0 frags of shift 0
  s16x8 S0 = *(const s16x8*)(Ash + ao[0]);
  s16x8 S1 = *(const s16x8*)(Ash + ao[1]);
  s16x8 S2 = *(const s16x8*)(Ash + ao[2]);
  s16x8 S3 = *(const s16x8*)(Ash + ao[3]);

  // ---- 25 shift-phases: 12 x (A-set, B-set) + tail A
  for (int k = 0; k < 12; ++k) {
    int sA = 2 * k + 2;                            // bfA reload shift
    int sB = 2 * k + 3; sB -= (sB >= 25) ? 25 : 0; // bfB reload (k=11 dummy)
    PHASE(bfA0, bfA1, bfA2, bfA3, bfA4, bfA5, bfA6, bfA7, sA)
    PHASE(bfB0, bfB1, bfB2, bfB3, bfB4, bfB5, bfB6, bfB7, sB)
  }
  PHASE(bfA0, bfA1, bfA2, bfA3, bfA4, bfA5, bfA6, bfA7, 1)  // s=24; dummy reload

  // ---- per-channel sum/sumsq from registers (valid rows only)
  float s1v[4] = {0.f, 0.f, 0.f, 0.f}, s2v[4] = {0.f, 0.f, 0.f, 0.f};
#pragma unroll
  for (int rt = 0; rt < 4; ++rt) {
#pragma unroll
    for (int qq = 0; qq < 4; ++qq) {
      int rloc = (wid << 6) + (rt << 4) + (lk << 2) + qq;  // C/D row
      if (rloc < validR) {
#pragma unroll
        for (int ct = 0; ct < 4; ++ct) {
          float val = acc[rt][ct][qq];
          s1v[ct] += val;
          s2v[ct] += val * val;
        }
      }
    }
  }
#pragma unroll
  for (int ct = 0; ct < 4; ++ct) {
    float a = s1v[ct], b = s2v[ct];
    a += __shfl_xor(a, 16); a += __shfl_xor(a, 32);
    b += __shfl_xor(b, 16); b += __shfl_xor(b, 32);
    if (lane < 16) {
      int base = ((((wid << 2) + ct) << 4) + l15) * 2;
      red2[base]     = a;
      red2[base + 1] = b;
    }
  }

  // ---- epilogue: 4 o-quarters through LDS transpose, coalesced f4 stores
  float* T = (float*)Ash;
  float* outb = out + n * 480000 + r0;     // + o*7500 + row
  for (int qt = 0; qt < 4; ++qt) {
    __syncthreads();   // qt=0: K-loop Ash reads + red2 writes done; else T reads
    // write acc[.][qt] -> T[o_local][row]
#pragma unroll
    for (int rt = 0; rt < 4; ++rt) {
      int row0 = (wid << 6) + (rt << 4) + (lk << 2);
      *(f32x4*)&T[l15 * TSTR + row0] = acc[rt][qt];
    }
    __syncthreads();
    if (qt == 0 && tid < 128) {   // deterministic partial reduction (reads red2)
      int o = tid >> 1, m = tid & 1;
      int ct = o >> 4, ol = o & 15;
      float sres = 0.f;
#pragma unroll
      for (int w = 0; w < 4; ++w) sres += red2[((((w << 2) + ct) << 4) + ol) * 2 + m];
      int bl = blockIdx.y * NBR_ + blockIdx.x;
      partials[bl * 128 + m * 64 + o] = sres;
    }
    // read T + coalesced global f4 stores: 16 o x 64 f4-rows
#pragma unroll
    for (int it = 0; it < 4; ++it) {
      int idx = tid + it * NTHR_;
      int ol = idx >> 6, r4 = idx & 63;
      if ((r4 << 2) < validR) {
        float4 v = *(float4*)&T[ol * TSTR + (r4 << 2)];
        *(float4*)&outb[((qt << 4) + ol) * 7500 + (r4 << 2)] = v;
      }
    }
  }
}

// --- P2: reduce per-block partials -> per-channel scale/shift --------------
__global__ void finalize_kernel(const float* __restrict__ part,
                                const float* __restrict__ gamma,
                                const float* __restrict__ beta,
                                float* __restrict__ scsh) {
  __shared__ float sm[512];
  int o = blockIdx.x;            // 64 blocks, one channel each
  int tid = threadIdx.x;         // 256 threads
  float s1 = 0.f, s2 = 0.f;
  for (int b = tid; b < 1920; b += 256) {
    s1 += part[b * 128 + o];
    s2 += part[b * 128 + 64 + o];
  }
  sm[tid] = s1; sm[256 + tid] = s2;
  __syncthreads();
  for (int st = 128; st >= 1; st >>= 1) {
    if (tid < st) { sm[tid] += sm[tid + st]; sm[256 + tid] += sm[256 + tid + st]; }
    __syncthreads();
  }
  if (tid == 0) {
    const float inv = 1.0f / 480000.0f;
    float mean = sm[0] * inv;
    float var  = sm[256] * inv - mean * mean;
    float sc = gamma[o] * rsqrtf(var + 1e-5f);
    float sh = beta[o] - mean * sc;
    scsh[o]      = sc;
    scsh[64 + o] = sh;
  }
}

// --- P3: in-place BN-apply + ReLU, float4 ----------------------------------
__global__ void bn_relu_kernel(float4* __restrict__ out, const float* __restrict__ scsh) {
  int i = blockIdx.x * blockDim.x + threadIdx.x;
  const int total = 7680000;        // 30.72M / 4 ; 7500%4==0 so o uniform per f4
  int stride = gridDim.x * blockDim.x;
  for (; i < total; i += stride) {
    int o = (i / 1875) & 63;
    float sc = scsh[o], sh = scsh[64 + o];
    float4 v = out[i];
    v.x = fmaxf(fmaf(v.x, sc, sh), 0.f);
    v.y = fmaxf(fmaf(v.y, sc, sh), 0.f);
    v.z = fmaxf(fmaf(v.z, sc, sh), 0.f);
    v.w = fmaxf(fmaf(v.w, sc, sh), 0.f);
    out[i] = v;
  }
}

// ---------------------------------------------------------------------------
extern "C" void kernel_launch(void* const* d_in, const int* in_sizes, int n_in,
                              void* d_out, int out_size, void* d_ws, size_t ws_size,
                              hipStream_t stream) {
  const float* x     = (const float*)d_in[0];
  const float* W     = (const float*)d_in[1];
  // d_in[2] = b : cancels under batch-norm, unused.
  const float* gamma = (const float*)d_in[3];
  const float* beta  = (const float*)d_in[4];
  float* out = (float*)d_out;

  char* ws = (char*)d_ws;
  s16x8* Wg       = (s16x8*)ws;                       // 204,800 B
  float* partials = (float*)(ws + 204800);            // 1920*128*4 = 983,040 B
  float* scsh     = (float*)(ws + 204800 + 983040);   // 512 B

  pack_w_kernel<<<dim3(50), dim3(256), 0, stream>>>(W, Wg);
  tap_mm_kernel<<<dim3(NBR_, 64), dim3(NTHR_), 0, stream>>>(x, Wg, out, partials);
  finalize_kernel<<<dim3(64), dim3(256), 0, stream>>>(partials, gamma, beta, scsh);
  bn_relu_kernel<<<dim3(2048), dim3(256), 0, stream>>>((float4*)out, scsh);
}

// Round 11
// 200.599 us; speedup vs baseline: 1.1669x; 1.1669x over previous
//
#include <hip/hip_runtime.h>

// ---------------------------------------------------------------------------
// unit_gcn: out[n,o,t,v] = BN+ReLU of  sum_{s=0..24} Ws[s] @_c x[n,:,t,(v+s)%25]
//   Ws[0] = sum_i W[i,:,:,0];  Ws[s] = W[s-1,:,:,1]  (s>=1); bias cancels in BN.
// N=64, C=64, T=300, V=25, O=64.  x fp32 -> bf16 MFMA (16x16x32), fp32 accum.
// v8 (R11): LDS-throughput model. 256thr/4 waves; wave = 32 rows x 64 o ->
// acc 32 VGPR, ~130 unified -> 3-4 waves/SIMD (the missing ingredient).
// A-slab: t-span window <=175 rows x 128B, XOR-swizzled (R2-verified);
// B global->reg parity ring (R9-verified). 4 substeps/shift {1 ds_read+4 MFMA}.
// ---------------------------------------------------------------------------

typedef short  s16x8 __attribute__((ext_vector_type(8)));
typedef float  f32x4 __attribute__((ext_vector_type(4)));

#define NTHR_   256
#define RPB_    128         // flat (t,v) rows per block
#define NBR_    59          // ceil(7500/128)
#define SLAB_   175         // slab rows: 7 t-windows x 25
#define TS_     132         // epilogue transpose stride (f32)

__device__ __forceinline__ unsigned short f2bf(float f) {
  unsigned u = __builtin_bit_cast(unsigned, f);
  return (unsigned short)((u + 0x7FFFu + ((u >> 16) & 1u)) >> 16);
}

// --- P0: pack Ws into MFMA B-fragment layout (s-major: q = s*2 + chunk) ----
// Wg entry idx = ((s*2+chunk)*4 + ni)*64 + lane ; 8 bf16 per entry:
//   elem j = Ws[s][ o = ni*16 + (lane&15) ][ c = chunk*32 + (lane>>4)*8 + j ]
__global__ void pack_w_kernel(const float* __restrict__ W, s16x8* __restrict__ Wg) {
  int idx = blockIdx.x * 256 + threadIdx.x;
  if (idx >= 12800) return;
  int lane  = idx & 63;
  int ni    = (idx >> 6) & 3;
  int chunk = (idx >> 8) & 1;
  int s     = idx >> 9;
  int o     = (ni << 4) + (lane & 15);
  int cbase = (chunk << 5) + ((lane >> 4) << 3);
  s16x8 h;
#pragma unroll
  for (int j = 0; j < 8; ++j) {
    int c = cbase + j;
    float val;
    if (s == 0) {
      val = 0.f;
      for (int i = 0; i < 24; ++i) val += W[((i * 64 + o) * 64 + c) * 2];
    } else {
      val = W[(((s - 1) * 64 + o) * 64 + c) * 2 + 1];
    }
    h[j] = (short)f2bf(val);
  }
  Wg[idx] = h;
}

// A-frag LDS byte offset: slab row sr, 16B-slot selector cc (= ch*64 | lk*16)
#define AOFF(SR, CC) (((SR) << 7) + ((CC) ^ (((SR) & 7) << 4)))

// 4 MFMAs into acc[RT][0..3]
#define MF4(RT, B0, B1, B2, B3, SR)                                              \
  acc[RT][0] = __builtin_amdgcn_mfma_f32_16x16x32_bf16(SR, B0, acc[RT][0], 0, 0, 0); \
  acc[RT][1] = __builtin_amdgcn_mfma_f32_16x16x32_bf16(SR, B1, acc[RT][1], 0, 0, 0); \
  acc[RT][2] = __builtin_amdgcn_mfma_f32_16x16x32_bf16(SR, B2, acc[RT][2], 0, 0, 0); \
  acc[RT][3] = __builtin_amdgcn_mfma_f32_16x16x32_bf16(SR, B3, acc[RT][3], 0, 0, 0);

// One shift (4 substeps, 16 MFMA). Entry: S0..S3 = frags(s,{rt,ch}) loaded
// during shift s-1. Each substep consumes one, loads the s+1 counterpart
// (next-shift slab rows sr0n/sr1n, computed without committing). B-set
// (8 frags) used throughout; reloaded at end for shift SN (= s+2).
#define PH(B0, B1, B2, B3, B4, B5, B6, B7, SN)                                   \
  {                                                                              \
    bool w0 = (u[0] == 24), w1 = (u[1] == 24);                                   \
    int sr0n = w0 ? sr[0] - 24 : sr[0] + 1;                                      \
    int sr1n = w1 ? sr[1] - 24 : sr[1] + 1;                                      \
    MF4(0, B0, B1, B2, B3, S0) S0 = *(const s16x8*)(Ash + AOFF(sr0n, cc0));      \
    MF4(1, B0, B1, B2, B3, S1) S1 = *(const s16x8*)(Ash + AOFF(sr1n, cc0));      \
    MF4(0, B4, B5, B6, B7, S2) S2 = *(const s16x8*)(Ash + AOFF(sr0n, cc1));      \
    MF4(1, B4, B5, B6, B7, S3) S3 = *(const s16x8*)(Ash + AOFF(sr1n, cc1));      \
    u[0] = w0 ? 0 : u[0] + 1; sr[0] = sr0n;                                      \
    u[1] = w1 ? 0 : u[1] + 1; sr[1] = sr1n;                                      \
    const s16x8* wq_ = Wg + (SN) * 512;                                          \
    B0 = wq_[lane];       B1 = wq_[64 + lane];                                   \
    B2 = wq_[128 + lane]; B3 = wq_[192 + lane];                                  \
    B4 = wq_[256 + lane]; B5 = wq_[320 + lane];                                  \
    B6 = wq_[384 + lane]; B7 = wq_[448 + lane];                                  \
  }

// --- P1: main tap-GEMM -----------------------------------------------------
// grid (br=59, n=64), 256 thr = 4 waves; wave owns 32 rows x 64 o.
__global__ __launch_bounds__(NTHR_) void tap_mm_kernel(
    const float* __restrict__ x, const s16x8* __restrict__ Wg,
    float* __restrict__ out, float* __restrict__ partials) {
  __shared__ __align__(16) char Ash[SLAB_ * 128];   // 22400B; epi T[16][132] f32
  __shared__ float red2[512];
  int br = blockIdx.x, n = blockIdx.y;
  int r0 = br * RPB_;
  int validR = min(RPB_, 7500 - r0);
  int t0g = r0 / 25;
  int tlast = (r0 + validR - 1) / 25;
  int slabRows = (tlast - t0g + 1) * 25;       // <= 175
  const float* xn = x + n * 480000;
  int xbase = t0g * 25;
  int tid = threadIdx.x;
  int wid = tid >> 6, lane = tid & 63;
  int l15 = lane & 15, lk = lane >> 4;
  int cc0 = lk << 4, cc1 = 64 | cc0;

  // ---- B prologue: shifts 0,1 (global, L2-hot; issue before staging)
  s16x8 bA0 = Wg[lane],       bA1 = Wg[64 + lane];
  s16x8 bA2 = Wg[128 + lane], bA3 = Wg[192 + lane];
  s16x8 bA4 = Wg[256 + lane], bA5 = Wg[320 + lane];
  s16x8 bA6 = Wg[384 + lane], bA7 = Wg[448 + lane];
  s16x8 bB0 = Wg[512 + lane], bB1 = Wg[576 + lane];
  s16x8 bB2 = Wg[640 + lane], bB3 = Wg[704 + lane];
  s16x8 bB4 = Wg[768 + lane], bB5 = Wg[832 + lane];
  s16x8 bB6 = Wg[896 + lane], bB7 = Wg[960 + lane];

  // ---- stage slab: 1400 tasks {8 strided c-loads -> XOR'd 16B ds_write}
#pragma unroll 3
  for (int it = 0; it < 6; ++it) {
    int id = tid + it * NTHR_;
    if (id < 1400) {
      int g = id / SLAB_, pos = id - g * SLAB_;   // g: 8-c group, pos: slab row
      bool vld = pos < slabRows;
      s16x8 h;
#pragma unroll
      for (int j = 0; j < 8; ++j) {
        float f = vld ? xn[((g << 3) + j) * 7500 + xbase + pos] : 0.f;
        h[j] = (short)f2bf(f);
      }
      *(s16x8*)(Ash + (((pos << 7) + (g << 4)) ^ ((pos & 7) << 4))) = h;
    }
  }

  int u[2], sr[2];
#pragma unroll
  for (int rt = 0; rt < 2; ++rt) {
    int gr = r0 + (wid << 5) + (rt << 4) + l15;   // A-side row this lane feeds
    int tL = gr / 25;
    u[rt]  = gr - tL * 25;                        // cycles with s, period 25
    sr[rt] = (tL - t0g) * 25 + u[rt];             // slab row (<= 174)
  }
  f32x4 acc[2][4];
#pragma unroll
  for (int rt = 0; rt < 2; ++rt)
#pragma unroll
    for (int ct = 0; ct < 4; ++ct) acc[rt][ct] = (f32x4){0.f, 0.f, 0.f, 0.f};

  __syncthreads();

  // ---- A-ring prologue: frags of shift 0
  s16x8 S0 = *(const s16x8*)(Ash + AOFF(sr[0], cc0));
  s16x8 S1 = *(const s16x8*)(Ash + AOFF(sr[1], cc0));
  s16x8 S2 = *(const s16x8*)(Ash + AOFF(sr[0], cc1));
  s16x8 S3 = *(const s16x8*)(Ash + AOFF(sr[1], cc1));

  // ---- 25 shifts: 12 x (A-set, B-set) + tail A
  for (int k = 0; k < 12; ++k) {
    int sA = 2 * k + 2;                            // bA reload shift
    int sB = 2 * k + 3; sB -= (sB >= 25) ? 25 : 0; // bB reload (k=11 dummy)
    PH(bA0, bA1, bA2, bA3, bA4, bA5, bA6, bA7, sA)
    PH(bB0, bB1, bB2, bB3, bB4, bB5, bB6, bB7, sB)
  }
  PH(bA0, bA1, bA2, bA3, bA4, bA5, bA6, bA7, 1)    // s=24; dummy reload

  // ---- per-channel sum/sumsq from registers (valid rows only)
  float s1v[4] = {0.f, 0.f, 0.f, 0.f}, s2v[4] = {0.f, 0.f, 0.f, 0.f};
#pragma unroll
  for (int rt = 0; rt < 2; ++rt) {
#pragma unroll
    for (int qq = 0; qq < 4; ++qq) {
      int rloc = (wid << 5) + (rt << 4) + (lk << 2) + qq;  // C/D row
      if (rloc < validR) {
#pragma unroll
        for (int ct = 0; ct < 4; ++ct) {
          float val = acc[rt][ct][qq];
          s1v[ct] += val;
          s2v[ct] += val * val;
        }
      }
    }
  }
#pragma unroll
  for (int ct = 0; ct < 4; ++ct) {
    float a = s1v[ct], b = s2v[ct];
    a += __shfl_xor(a, 16); a += __shfl_xor(a, 32);
    b += __shfl_xor(b, 16); b += __shfl_xor(b, 32);
    if (lane < 16) {
      int base = ((((wid << 2) + ct) << 4) + l15) * 2;
      red2[base]     = a;
      red2[base + 1] = b;
    }
  }

  // ---- epilogue: 4 o-quarters via LDS transpose, coalesced f4 stores
  float* T = (float*)Ash;
  float* outb = out + n * 480000 + r0;     // + o*7500 + row
  for (int qt = 0; qt < 4; ++qt) {
    __syncthreads();   // qt=0: slab reads + red2 writes done; else T reads done
    // write acc[.][qt] -> T[o_local][row]
#pragma unroll
    for (int rt = 0; rt < 2; ++rt) {
      int row0 = (wid << 5) + (rt << 4) + (lk << 2);
      *(f32x4*)&T[l15 * TS_ + row0] = acc[rt][qt];
    }
    __syncthreads();
    if (qt == 0 && tid < 128) {   // deterministic partial reduction (reads red2)
      int o = tid >> 1, m = tid & 1;
      int ct = o >> 4, ol = o & 15;
      float sres = 0.f;
#pragma unroll
      for (int w = 0; w < 4; ++w) sres += red2[((((w << 2) + ct) << 4) + ol) * 2 + m];
      int bl = blockIdx.y * NBR_ + blockIdx.x;
      partials[bl * 128 + m * 64 + o] = sres;
    }
    // read T + coalesced global f4 stores: 16 o x 32 f4-rows
#pragma unroll
    for (int it = 0; it < 2; ++it) {
      int idx = tid + it * NTHR_;
      int ol = idx >> 5, r4 = idx & 31;
      if ((r4 << 2) < validR) {
        float4 v = *(float4*)&T[ol * TS_ + (r4 << 2)];
        *(float4*)&outb[((qt << 4) + ol) * 7500 + (r4 << 2)] = v;
      }
    }
  }
}

// --- P2: reduce per-block partials -> per-channel scale/shift --------------
__global__ void finalize_kernel(const float* __restrict__ part,
                                const float* __restrict__ gamma,
                                const float* __restrict__ beta,
                                float* __restrict__ scsh) {
  __shared__ float sm[512];
  int o = blockIdx.x;            // 64 blocks, one channel each
  int tid = threadIdx.x;         // 256 threads
  float s1 = 0.f, s2 = 0.f;
  for (int b = tid; b < 64 * NBR_; b += 256) {
    s1 += part[b * 128 + o];
    s2 += part[b * 128 + 64 + o];
  }
  sm[tid] = s1; sm[256 + tid] = s2;
  __syncthreads();
  for (int st = 128; st >= 1; st >>= 1) {
    if (tid < st) { sm[tid] += sm[tid + st]; sm[256 + tid] += sm[256 + tid + st]; }
    __syncthreads();
  }
  if (tid == 0) {
    const float inv = 1.0f / 480000.0f;
    float mean = sm[0] * inv;
    float var  = sm[256] * inv - mean * mean;
    float sc = gamma[o] * rsqrtf(var + 1e-5f);
    float sh = beta[o] - mean * sc;
    scsh[o]      = sc;
    scsh[64 + o] = sh;
  }
}

// --- P3: in-place BN-apply + ReLU, float4 ----------------------------------
__global__ void bn_relu_kernel(float4* __restrict__ out, const float* __restrict__ scsh) {
  int i = blockIdx.x * blockDim.x + threadIdx.x;
  const int total = 7680000;        // 30.72M / 4 ; 7500%4==0 so o uniform per f4
  int stride = gridDim.x * blockDim.x;
  for (; i < total; i += stride) {
    int o = (i / 1875) & 63;
    float sc = scsh[o], sh = scsh[64 + o];
    float4 v = out[i];
    v.x = fmaxf(fmaf(v.x, sc, sh), 0.f);
    v.y = fmaxf(fmaf(v.y, sc, sh), 0.f);
    v.z = fmaxf(fmaf(v.z, sc, sh), 0.f);
    v.w = fmaxf(fmaf(v.w, sc, sh), 0.f);
    out[i] = v;
  }
}

// ---------------------------------------------------------------------------
extern "C" void kernel_launch(void* const* d_in, const int* in_sizes, int n_in,
                              void* d_out, int out_size, void* d_ws, size_t ws_size,
                              hipStream_t stream) {
  const float* x     = (const float*)d_in[0];
  const float* W     = (const float*)d_in[1];
  // d_in[2] = b : cancels under batch-norm, unused.
  const float* gamma = (const float*)d_in[3];
  const float* beta  = (const float*)d_in[4];
  float* out = (float*)d_out;

  char* ws = (char*)d_ws;
  s16x8* Wg       = (s16x8*)ws;                        // 204,800 B
  float* partials = (float*)(ws + 204800);             // 3776*128*4 = 1,933,312 B
  float* scsh     = (float*)(ws + 204800 + 1933312);   // 512 B

  pack_w_kernel<<<dim3(50), dim3(256), 0, stream>>>(W, Wg);
  tap_mm_kernel<<<dim3(NBR_, 64), dim3(NTHR_), 0, stream>>>(x, Wg, out, partials);
  finalize_kernel<<<dim3(64), dim3(256), 0, stream>>>(partials, gamma, beta, scsh);
  bn_relu_kernel<<<dim3(2048), dim3(256), 0, stream>>>((float4*)out, scsh);
}

// Round 12
// 184.938 us; speedup vs baseline: 1.2657x; 1.0847x over previous
//
#include <hip/hip_runtime.h>

// ---------------------------------------------------------------------------
// unit_gcn: out[n,o,t,v] = BN+ReLU of  sum_{s=0..24} Ws[s] @_c x[n,:,t,(v+s)%25]
//   Ws[0] = sum_i W[i,:,:,0];  Ws[s] = W[s-1,:,:,1]  (s>=1); bias cancels in BN.
// N=64, C=64, T=300, V=25, O=64.  x fp32 -> bf16 MFMA (16x16x32), fp32 accum.
// v9 (R12): B block-shared in LDS (2x8KB double buffer, issue-early/write-late
// reg staging, one barrier per shift); A-slab 256x128B XOR-swizzled; block =
// 250 rows (25-aligned, no edge masks), 4 waves x (64 rows x 64 o);
// 51.2KB LDS -> 3 blocks/CU; ~156 regs -> 3 waves/SIMD.
// ---------------------------------------------------------------------------

typedef short  s16x8 __attribute__((ext_vector_type(8)));
typedef float  f32x4 __attribute__((ext_vector_type(4)));

#define NTHR_   256
#define RPB_    250         // rows per block (exactly 10 t x 25 v)
#define NBR_    30          // 7500 / 250
#define TS_     260         // epilogue transpose stride (f32)

__device__ __forceinline__ unsigned short f2bf(float f) {
  unsigned u = __builtin_bit_cast(unsigned, f);
  return (unsigned short)((u + 0x7FFFu + ((u >> 16) & 1u)) >> 16);
}

// --- P0: pack Ws into MFMA B-fragment layout (s-major: q = s*2 + chunk) ----
// Wg entry idx = ((s*2+chunk)*4 + ni)*64 + lane ; 8 bf16 per entry:
//   elem j = Ws[s][ o = ni*16 + (lane&15) ][ c = chunk*32 + (lane>>4)*8 + j ]
__global__ void pack_w_kernel(const float* __restrict__ W, s16x8* __restrict__ Wg) {
  int idx = blockIdx.x * 256 + threadIdx.x;
  if (idx >= 12800) return;
  int lane  = idx & 63;
  int ni    = (idx >> 6) & 3;
  int chunk = (idx >> 8) & 1;
  int s     = idx >> 9;
  int o     = (ni << 4) + (lane & 15);
  int cbase = (chunk << 5) + ((lane >> 4) << 3);
  s16x8 h;
#pragma unroll
  for (int j = 0; j < 8; ++j) {
    int c = cbase + j;
    float val;
    if (s == 0) {
      val = 0.f;
      for (int i = 0; i < 24; ++i) val += W[((i * 64 + o) * 64 + c) * 2];
    } else {
      val = W[(((s - 1) * 64 + o) * 64 + c) * 2 + 1];
    }
    h[j] = (short)f2bf(val);
  }
  Wg[idx] = h;
}

// A-frag LDS byte offset: slab row SR, slot CC (= ch*64 + lk*16), XOR swizzle
#define AOFF(SR, CC) (((SR) << 7) + ((CC) ^ (((SR) & 7) << 4)))
// advance row-tile J's shift state (period 25)
#define ADV(J) { bool w_ = (u[J] == 24); u[J] = w_ ? 0 : u[J] + 1; \
                 sr[J] += w_ ? -24 : 1; }
// one MFMA
#define MM(RT, CT, AF, BF) \
  acc[RT][CT] = __builtin_amdgcn_mfma_f32_16x16x32_bf16(AF, BF, acc[RT][CT], 0, 0, 0);

// One shift s (buffer BB = s&1). Entry: Ap0-3/Bp0-3 = ch0 frags of s.
// PH_A: 16 MFMA (ch0) + read Aq/Bq (ch1 of s; B from Bsh[BB]).
// barrier. PH_B: 16 MFMA (ch1) + read Ap/Bp (ch0 of s+1; B from Bsh[BB^1],
// published at barrier of s-1). Then write B(s+2) (reg-staged, loaded at
// shift top) into Bsh[BB]. Hazards separated by the single barrier.
#define SHIFT(S_, BB)                                                          \
  {                                                                            \
    int sc_ = (S_) + 2; sc_ = (sc_ > 24) ? 24 : sc_;                           \
    const s16x8* ws_ = Wg + sc_ * 512;                                         \
    s16x8 Br0_ = ws_[tid], Br1_ = ws_[256 + tid];                              \
    const char* bq_ = Bsh + (BB) * 8192 + 4096 + (lane << 4);                  \
    __builtin_amdgcn_s_setprio(1);                                             \
    Aq0 = *(const s16x8*)(Ash + AOFF(sr[0], cc1));                             \
    MM(0, 0, Ap0, Bp0) MM(0, 1, Ap0, Bp1)                                      \
    Bq0 = *(const s16x8*)(bq_);                                                \
    MM(0, 2, Ap0, Bp2) MM(0, 3, Ap0, Bp3)                                      \
    Aq1 = *(const s16x8*)(Ash + AOFF(sr[1], cc1));                             \
    MM(1, 0, Ap1, Bp0) MM(1, 1, Ap1, Bp1)                                      \
    Bq1 = *(const s16x8*)(bq_ + 1024);                                         \
    MM(1, 2, Ap1, Bp2) MM(1, 3, Ap1, Bp3)                                      \
    Aq2 = *(const s16x8*)(Ash + AOFF(sr[2], cc1));                             \
    MM(2, 0, Ap2, Bp0) MM(2, 1, Ap2, Bp1)                                      \
    Bq2 = *(const s16x8*)(bq_ + 2048);                                         \
    MM(2, 2, Ap2, Bp2) MM(2, 3, Ap2, Bp3)                                      \
    Aq3 = *(const s16x8*)(Ash + AOFF(sr[3], cc1));                             \
    MM(3, 0, Ap3, Bp0) MM(3, 1, Ap3, Bp1)                                      \
    Bq3 = *(const s16x8*)(bq_ + 3072);                                         \
    MM(3, 2, Ap3, Bp2) MM(3, 3, Ap3, Bp3)                                      \
    __builtin_amdgcn_s_setprio(0);                                             \
    __syncthreads();                                                           \
    const char* bp_ = Bsh + (((BB) ^ 1) * 8192) + (lane << 4);                 \
    __builtin_amdgcn_s_setprio(1);                                             \
    ADV(0) Ap0 = *(const s16x8*)(Ash + AOFF(sr[0], cc0));                      \
    MM(0, 0, Aq0, Bq0) MM(0, 1, Aq0, Bq1)                                      \
    Bp0 = *(const s16x8*)(bp_);                                                \
    MM(0, 2, Aq0, Bq2) MM(0, 3, Aq0, Bq3)                                      \
    ADV(1) Ap1 = *(const s16x8*)(Ash + AOFF(sr[1], cc0));                      \
    MM(1, 0, Aq1, Bq0) MM(1, 1, Aq1, Bq1)                                      \
    Bp1 = *(const s16x8*)(bp_ + 1024);                                         \
    MM(1, 2, Aq1, Bq2) MM(1, 3, Aq1, Bq3)                                      \
    ADV(2) Ap2 = *(const s16x8*)(Ash + AOFF(sr[2], cc0));                      \
    MM(2, 0, Aq2, Bq0) MM(2, 1, Aq2, Bq1)                                      \
    Bp2 = *(const s16x8*)(bp_ + 2048);                                         \
    MM(2, 2, Aq2, Bq2) MM(2, 3, Aq2, Bq3)                                      \
    ADV(3) Ap3 = *(const s16x8*)(Ash + AOFF(sr[3], cc0));                      \
    MM(3, 0, Aq3, Bq0) MM(3, 1, Aq3, Bq1)                                      \
    Bp3 = *(const s16x8*)(bp_ + 3072);                                         \
    MM(3, 2, Aq3, Bq2) MM(3, 3, Aq3, Bq3)                                      \
    __builtin_amdgcn_s_setprio(0);                                             \
    *(s16x8*)(Bsh + (BB) * 8192 + (tid << 4)) = Br0_;                          \
    *(s16x8*)(Bsh + (BB) * 8192 + 4096 + (tid << 4)) = Br1_;                   \
  }

// --- P1: main tap-GEMM -----------------------------------------------------
// grid (br=30, n=64), 256 thr = 4 waves; wave owns 64 rows x 64 o.
__global__ __launch_bounds__(NTHR_) void tap_mm_kernel(
    const float* __restrict__ x, const s16x8* __restrict__ Wg,
    float* __restrict__ out, float* __restrict__ partials) {
  __shared__ __align__(16) char Ash[32768];   // A-slab 256x128B; epi T[16][260]
  __shared__ __align__(16) char Bsh[16384];   // B double buffer 2 x 8KB
  __shared__ float red2[512];
  int br = blockIdx.x, n = blockIdx.y;
  int r0 = br * RPB_;                 // also = xbase (t0g*25), 25-aligned
  const float* xn = x + n * 480000 + r0;
  int tid = threadIdx.x;
  int wid = tid >> 6, lane = tid & 63;
  int l15 = lane & 15, lk = lane >> 4;
  int cc0 = lk << 4, cc1 = 64 + cc0;

  // ---- B prologue: shifts 0 and 1 -> regs (L2-hot)
  s16x8 p0 = Wg[tid], p1 = Wg[256 + tid], p2 = Wg[512 + tid], p3 = Wg[768 + tid];

  // ---- stage A slab: iteration it stages c-group it across 256 rows
#pragma unroll 2
  for (int it = 0; it < 8; ++it) {
    int pos = tid;                    // slab row (250..255 -> zero pad)
    bool vld = pos < RPB_;
    s16x8 h;
#pragma unroll
    for (int j = 0; j < 8; ++j) {
      float f = vld ? xn[((it << 3) + j) * 7500 + pos] : 0.f;
      h[j] = (short)f2bf(f);
    }
    *(s16x8*)(Ash + (((pos << 7) + (it << 4)) ^ ((pos & 7) << 4))) = h;
  }
  // B(0) -> Bsh[0], B(1) -> Bsh[1]
  *(s16x8*)(Bsh + (tid << 4))         = p0;
  *(s16x8*)(Bsh + 4096 + (tid << 4))  = p1;
  *(s16x8*)(Bsh + 8192 + (tid << 4))  = p2;
  *(s16x8*)(Bsh + 12288 + (tid << 4)) = p3;

  // ---- per-lane A row state
  int u[4], sr[4];
#pragma unroll
  for (int rt = 0; rt < 4; ++rt) {
    int gr = r0 + (wid << 6) + (rt << 4) + l15;  // global flat row (A-side)
    int tL = gr / 25;
    u[rt]  = gr - tL * 25;
    sr[rt] = (wid << 6) + (rt << 4) + l15;       // local slab row
  }
  f32x4 acc[4][4];
#pragma unroll
  for (int rt = 0; rt < 4; ++rt)
#pragma unroll
    for (int ct = 0; ct < 4; ++ct) acc[rt][ct] = (f32x4){0.f, 0.f, 0.f, 0.f};

  __syncthreads();

  // ---- preload ch0 frags of shift 0
  s16x8 Ap0 = *(const s16x8*)(Ash + AOFF(sr[0], cc0));
  s16x8 Ap1 = *(const s16x8*)(Ash + AOFF(sr[1], cc0));
  s16x8 Ap2 = *(const s16x8*)(Ash + AOFF(sr[2], cc0));
  s16x8 Ap3 = *(const s16x8*)(Ash + AOFF(sr[3], cc0));
  const char* b0_ = Bsh + (lane << 4);
  s16x8 Bp0 = *(const s16x8*)(b0_);
  s16x8 Bp1 = *(const s16x8*)(b0_ + 1024);
  s16x8 Bp2 = *(const s16x8*)(b0_ + 2048);
  s16x8 Bp3 = *(const s16x8*)(b0_ + 3072);
  s16x8 Aq0, Aq1, Aq2, Aq3, Bq0, Bq1, Bq2, Bq3;

  // ---- 25 shifts (buffer parity = s&1)
  for (int k = 0; k < 12; ++k) {
    SHIFT(2 * k, 0)
    SHIFT(2 * k + 1, 1)
  }
  SHIFT(24, 0)

  // ---- per-channel sum/sumsq from registers (rows < 250 only)
  float s1v[4] = {0.f, 0.f, 0.f, 0.f}, s2v[4] = {0.f, 0.f, 0.f, 0.f};
#pragma unroll
  for (int rt = 0; rt < 4; ++rt) {
#pragma unroll
    for (int qq = 0; qq < 4; ++qq) {
      int rloc = (wid << 6) + (rt << 4) + (lk << 2) + qq;  // C/D row
      if (rloc < RPB_) {
#pragma unroll
        for (int ct = 0; ct < 4; ++ct) {
          float val = acc[rt][ct][qq];
          s1v[ct] += val;
          s2v[ct] += val * val;
        }
      }
    }
  }
#pragma unroll
  for (int ct = 0; ct < 4; ++ct) {
    float a = s1v[ct], b = s2v[ct];
    a += __shfl_xor(a, 16); a += __shfl_xor(a, 32);
    b += __shfl_xor(b, 16); b += __shfl_xor(b, 32);
    if (lane < 16) {
      int base = ((((wid << 2) + ct) << 4) + l15) * 2;
      red2[base]     = a;
      red2[base + 1] = b;
    }
  }

  // ---- epilogue: 4 o-quarters via LDS transpose, coalesced float2 stores
  float* T = (float*)Ash;
  float* outb = out + n * 480000 + r0;     // + o*7500 + row
#pragma unroll
  for (int qt = 0; qt < 4; ++qt) {
    __syncthreads();   // qt=0: K-loop LDS reads + red2 writes done; else T reads
#pragma unroll
    for (int rt = 0; rt < 4; ++rt) {
      int row0 = (wid << 6) + (rt << 4) + (lk << 2);
      *(f32x4*)&T[l15 * TS_ + row0] = acc[rt][qt];
    }
    __syncthreads();
    if (qt == 0 && tid < 128) {   // deterministic partial reduction
      int o = tid >> 1, m = tid & 1;
      int ct = o >> 4, ol = o & 15;
      float sres = 0.f;
#pragma unroll
      for (int w = 0; w < 4; ++w)
        sres += red2[((((w << 2) + ct) << 4) + ol) * 2 + m];
      int bl = n * NBR_ + br;
      partials[bl * 128 + m * 64 + o] = sres;
    }
    // stores: 16 o x 125 float2 rows (250 rows, 8B aligned for any br)
#pragma unroll
    for (int it = 0; it < 8; ++it) {
      int idx = tid + it * NTHR_;
      if (idx < 2000) {
        int ol = idx / 125, r2 = idx - ol * 125;
        *(float2*)&outb[((qt << 4) + ol) * 7500 + (r2 << 1)] =
            *(float2*)&T[ol * TS_ + (r2 << 1)];
      }
    }
  }
}

// --- P2: reduce per-block partials -> per-channel scale/shift --------------
__global__ void finalize_kernel(const float* __restrict__ part,
                                const float* __restrict__ gamma,
                                const float* __restrict__ beta,
                                float* __restrict__ scsh) {
  __shared__ float sm[512];
  int o = blockIdx.x;            // 64 blocks, one channel each
  int tid = threadIdx.x;         // 256 threads
  float s1 = 0.f, s2 = 0.f;
  for (int b = tid; b < 64 * NBR_; b += 256) {
    s1 += part[b * 128 + o];
    s2 += part[b * 128 + 64 + o];
  }
  sm[tid] = s1; sm[256 + tid] = s2;
  __syncthreads();
  for (int st = 128; st >= 1; st >>= 1) {
    if (tid < st) { sm[tid] += sm[tid + st]; sm[256 + tid] += sm[256 + tid + st]; }
    __syncthreads();
  }
  if (tid == 0) {
    const float inv = 1.0f / 480000.0f;
    float mean = sm[0] * inv;
    float var  = sm[256] * inv - mean * mean;
    float sc = gamma[o] * rsqrtf(var + 1e-5f);
    float sh = beta[o] - mean * sc;
    scsh[o]      = sc;
    scsh[64 + o] = sh;
  }
}

// --- P3: in-place BN-apply + ReLU, float4 ----------------------------------
__global__ void bn_relu_kernel(float4* __restrict__ out, const float* __restrict__ scsh) {
  int i = blockIdx.x * blockDim.x + threadIdx.x;
  const int total = 7680000;        // 30.72M / 4 ; 7500%4==0 so o uniform per f4
  int stride = gridDim.x * blockDim.x;
  for (; i < total; i += stride) {
    int o = (i / 1875) & 63;
    float sc = scsh[o], sh = scsh[64 + o];
    float4 v = out[i];
    v.x = fmaxf(fmaf(v.x, sc, sh), 0.f);
    v.y = fmaxf(fmaf(v.y, sc, sh), 0.f);
    v.z = fmaxf(fmaf(v.z, sc, sh), 0.f);
    v.w = fmaxf(fmaf(v.w, sc, sh), 0.f);
    out[i] = v;
  }
}

// ---------------------------------------------------------------------------
extern "C" void kernel_launch(void* const* d_in, const int* in_sizes, int n_in,
                              void* d_out, int out_size, void* d_ws, size_t ws_size,
                              hipStream_t stream) {
  const float* x     = (const float*)d_in[0];
  const float* W     = (const float*)d_in[1];
  // d_in[2] = b : cancels under batch-norm, unused.
  const float* gamma = (const float*)d_in[3];
  const float* beta  = (const float*)d_in[4];
  float* out = (float*)d_out;

  char* ws = (char*)d_ws;
  s16x8* Wg       = (s16x8*)ws;                       // 204,800 B
  float* partials = (float*)(ws + 204800);            // 1920*128*4 = 983,040 B
  float* scsh     = (float*)(ws + 204800 + 983040);   // 512 B

  pack_w_kernel<<<dim3(50), dim3(256), 0, stream>>>(W, Wg);
  tap_mm_kernel<<<dim3(NBR_, 64), dim3(NTHR_), 0, stream>>>(x, Wg, out, partials);
  finalize_kernel<<<dim3(64), dim3(256), 0, stream>>>(partials, gamma, beta, scsh);
  bn_relu_kernel<<<dim3(2048), dim3(256), 0, stream>>>((float4*)out, scsh);
}

// Round 13
// 180.814 us; speedup vs baseline: 1.2945x; 1.0228x over previous
//
#include <hip/hip_runtime.h>

// ---------------------------------------------------------------------------
// unit_gcn: out[n,o,t,v] = BN+ReLU of  sum_{s=0..24} Ws[s] @_c x[n,:,t,(v+s)%25]
//   Ws[0] = sum_i W[i,:,:,0];  Ws[s] = W[s-1,:,:,1]  (s>=1); bias cancels in BN.
// N=64, C=64, T=300, V=25, O=64.  x fp32 -> bf16 MFMA (16x16x32), fp32 accum.
// v10 (R13): R12 structure + TRANSPOSED A-slab A_T[slot][row] (slot=c-group):
// bank-even b128 reads with NO swizzle, A addr update = 1 cond-add/row-tile,
// ch1 via offset:16384. B block-shared 2x8KB dbuf (R12-verified), one barrier
// per shift. 51.2KB LDS -> 3 blocks/CU; ~160 unified regs -> 3 waves/SIMD.
// ---------------------------------------------------------------------------

typedef short  s16x8 __attribute__((ext_vector_type(8)));
typedef float  f32x4 __attribute__((ext_vector_type(4)));

#define NTHR_   256
#define RPB_    250         // rows per block (exactly 10 t x 25 v)
#define NBR_    30          // 7500 / 250
#define TS_     260         // epilogue transpose stride (f32)

__device__ __forceinline__ unsigned short f2bf(float f) {
  unsigned u = __builtin_bit_cast(unsigned, f);
  return (unsigned short)((u + 0x7FFFu + ((u >> 16) & 1u)) >> 16);
}

// --- P0: pack Ws into MFMA B-fragment layout (s-major: q = s*2 + chunk) ----
// Wg entry idx = ((s*2+chunk)*4 + ni)*64 + lane ; 8 bf16 per entry:
//   elem j = Ws[s][ o = ni*16 + (lane&15) ][ c = chunk*32 + (lane>>4)*8 + j ]
__global__ void pack_w_kernel(const float* __restrict__ W, s16x8* __restrict__ Wg) {
  int idx = blockIdx.x * 256 + threadIdx.x;
  if (idx >= 12800) return;
  int lane  = idx & 63;
  int ni    = (idx >> 6) & 3;
  int chunk = (idx >> 8) & 1;
  int s     = idx >> 9;
  int o     = (ni << 4) + (lane & 15);
  int cbase = (chunk << 5) + ((lane >> 4) << 3);
  s16x8 h;
#pragma unroll
  for (int j = 0; j < 8; ++j) {
    int c = cbase + j;
    float val;
    if (s == 0) {
      val = 0.f;
      for (int i = 0; i < 24; ++i) val += W[((i * 64 + o) * 64 + c) * 2];
    } else {
      val = W[(((s - 1) * 64 + o) * 64 + c) * 2 + 1];
    }
    h[j] = (short)f2bf(val);
  }
  Wg[idx] = h;
}

// advance row-tile J's shift state (period 25); aoc is byte offset into Ash
#define ADV(J) { bool w_ = (u[J] == 24); u[J] = w_ ? 0 : u[J] + 1; \
                 aoc[J] += w_ ? -384 : 16; }
// one MFMA
#define MM(RT, CT, AF, BF) \
  acc[RT][CT] = __builtin_amdgcn_mfma_f32_16x16x32_bf16(AF, BF, acc[RT][CT], 0, 0, 0);

// One shift s (buffer BB = s&1). Entry: Ap0-3/Bp0-3 = ch0 frags of s.
// PH_A: 16 MFMA (ch0) + read Aq/Bq (ch1 of s; A at +16384, B from Bsh[BB]).
// barrier. PH_B: 16 MFMA (ch1) + read Ap/Bp (ch0 of s+1; B from Bsh[BB^1]).
// Then write B(s+2) (reg-staged at shift top) into Bsh[BB].
#define SHIFT(S_, BB)                                                          \
  {                                                                            \
    int sc_ = (S_) + 2; sc_ = (sc_ > 24) ? 24 : sc_;                           \
    const s16x8* ws_ = Wg + sc_ * 512;                                         \
    s16x8 Br0_ = ws_[tid], Br1_ = ws_[256 + tid];                              \
    const char* bq_ = Bsh + (BB) * 8192 + 4096 + (lane << 4);                  \
    __builtin_amdgcn_s_setprio(1);                                             \
    Aq0 = *(const s16x8*)(Ash + aoc[0] + 16384);                               \
    MM(0, 0, Ap0, Bp0) MM(0, 1, Ap0, Bp1)                                      \
    Bq0 = *(const s16x8*)(bq_);                                                \
    MM(0, 2, Ap0, Bp2) MM(0, 3, Ap0, Bp3)                                      \
    Aq1 = *(const s16x8*)(Ash + aoc[1] + 16384);                               \
    MM(1, 0, Ap1, Bp0) MM(1, 1, Ap1, Bp1)                                      \
    Bq1 = *(const s16x8*)(bq_ + 1024);                                         \
    MM(1, 2, Ap1, Bp2) MM(1, 3, Ap1, Bp3)                                      \
    Aq2 = *(const s16x8*)(Ash + aoc[2] + 16384);                               \
    MM(2, 0, Ap2, Bp0) MM(2, 1, Ap2, Bp1)                                      \
    Bq2 = *(const s16x8*)(bq_ + 2048);                                         \
    MM(2, 2, Ap2, Bp2) MM(2, 3, Ap2, Bp3)                                      \
    Aq3 = *(const s16x8*)(Ash + aoc[3] + 16384);                               \
    MM(3, 0, Ap3, Bp0) MM(3, 1, Ap3, Bp1)                                      \
    Bq3 = *(const s16x8*)(bq_ + 3072);                                         \
    MM(3, 2, Ap3, Bp2) MM(3, 3, Ap3, Bp3)                                      \
    __builtin_amdgcn_s_setprio(0);                                             \
    __syncthreads();                                                           \
    const char* bp_ = Bsh + (((BB) ^ 1) * 8192) + (lane << 4);                 \
    __builtin_amdgcn_s_setprio(1);                                             \
    ADV(0) Ap0 = *(const s16x8*)(Ash + aoc[0]);                                \
    MM(0, 0, Aq0, Bq0) MM(0, 1, Aq0, Bq1)                                      \
    Bp0 = *(const s16x8*)(bp_);                                                \
    MM(0, 2, Aq0, Bq2) MM(0, 3, Aq0, Bq3)                                      \
    ADV(1) Ap1 = *(const s16x8*)(Ash + aoc[1]);                                \
    MM(1, 0, Aq1, Bq0) MM(1, 1, Aq1, Bq1)                                      \
    Bp1 = *(const s16x8*)(bp_ + 1024);                                         \
    MM(1, 2, Aq1, Bq2) MM(1, 3, Aq1, Bq3)                                      \
    ADV(2) Ap2 = *(const s16x8*)(Ash + aoc[2]);                                \
    MM(2, 0, Aq2, Bq0) MM(2, 1, Aq2, Bq1)                                      \
    Bp2 = *(const s16x8*)(bp_ + 2048);                                         \
    MM(2, 2, Aq2, Bq2) MM(2, 3, Aq2, Bq3)                                      \
    ADV(3) Ap3 = *(const s16x8*)(Ash + aoc[3]);                                \
    MM(3, 0, Aq3, Bq0) MM(3, 1, Aq3, Bq1)                                      \
    Bp3 = *(const s16x8*)(bp_ + 3072);                                         \
    MM(3, 2, Aq3, Bq2) MM(3, 3, Aq3, Bq3)                                      \
    __builtin_amdgcn_s_setprio(0);                                             \
    *(s16x8*)(Bsh + (BB) * 8192 + (tid << 4)) = Br0_;                          \
    *(s16x8*)(Bsh + (BB) * 8192 + 4096 + (tid << 4)) = Br1_;                   \
  }

// --- P1: main tap-GEMM -----------------------------------------------------
// grid (br=30, n=64), 256 thr = 4 waves; wave owns 64 rows x 64 o.
// A-slab TRANSPOSED: A_T[slot 0..7][row 0..255] 16B frags; slot = c-group,
// frag(row, ch) for lane: addr = (ch*4 + lk)*4096 + row*16.
__global__ __launch_bounds__(NTHR_) void tap_mm_kernel(
    const float* __restrict__ x, const s16x8* __restrict__ Wg,
    float* __restrict__ out, float* __restrict__ partials) {
  __shared__ __align__(16) char Ash[32768];   // A_T 8x256x16B; epi T[16][260]
  __shared__ __align__(16) char Bsh[16384];   // B double buffer 2 x 8KB
  __shared__ float red2[512];
  int br = blockIdx.x, n = blockIdx.y;
  int r0 = br * RPB_;                 // 25-aligned
  const float* xn = x + n * 480000 + r0;
  int tid = threadIdx.x;
  int wid = tid >> 6, lane = tid & 63;
  int l15 = lane & 15, lk = lane >> 4;

  // ---- B prologue: shifts 0 and 1 -> regs (L2-hot)
  s16x8 p0 = Wg[tid], p1 = Wg[256 + tid], p2 = Wg[512 + tid], p3 = Wg[768 + tid];

  // ---- stage A_T: iteration it = slot; row = tid (250..255 zero pad)
#pragma unroll 2
  for (int it = 0; it < 8; ++it) {
    bool vld = tid < RPB_;
    s16x8 h;
#pragma unroll
    for (int j = 0; j < 8; ++j) {
      float f = vld ? xn[((it << 3) + j) * 7500 + tid] : 0.f;
      h[j] = (short)f2bf(f);
    }
    *(s16x8*)(Ash + (it << 12) + (tid << 4)) = h;
  }
  // B(0) -> Bsh[0], B(1) -> Bsh[1]
  *(s16x8*)(Bsh + (tid << 4))         = p0;
  *(s16x8*)(Bsh + 4096 + (tid << 4))  = p1;
  *(s16x8*)(Bsh + 8192 + (tid << 4))  = p2;
  *(s16x8*)(Bsh + 12288 + (tid << 4)) = p3;

  // ---- per-lane A row state: aoc = lk*4096 + srow*16 (ch0 byte offset)
  int u[4], aoc[4];
#pragma unroll
  for (int rt = 0; rt < 4; ++rt) {
    int srow = (wid << 6) + (rt << 4) + l15;     // local slab row (A-side)
    u[rt]   = srow % 25;                         // r0 is 25-aligned
    aoc[rt] = (lk << 12) + (srow << 4);
  }
  f32x4 acc[4][4];
#pragma unroll
  for (int rt = 0; rt < 4; ++rt)
#pragma unroll
    for (int ct = 0; ct < 4; ++ct) acc[rt][ct] = (f32x4){0.f, 0.f, 0.f, 0.f};

  __syncthreads();

  // ---- preload ch0 frags of shift 0
  s16x8 Ap0 = *(const s16x8*)(Ash + aoc[0]);
  s16x8 Ap1 = *(const s16x8*)(Ash + aoc[1]);
  s16x8 Ap2 = *(const s16x8*)(Ash + aoc[2]);
  s16x8 Ap3 = *(const s16x8*)(Ash + aoc[3]);
  const char* b0_ = Bsh + (lane << 4);
  s16x8 Bp0 = *(const s16x8*)(b0_);
  s16x8 Bp1 = *(const s16x8*)(b0_ + 1024);
  s16x8 Bp2 = *(const s16x8*)(b0_ + 2048);
  s16x8 Bp3 = *(const s16x8*)(b0_ + 3072);
  s16x8 Aq0, Aq1, Aq2, Aq3, Bq0, Bq1, Bq2, Bq3;

  // ---- 25 shifts (buffer parity = s&1)
  for (int k = 0; k < 12; ++k) {
    SHIFT(2 * k, 0)
    SHIFT(2 * k + 1, 1)
  }
  SHIFT(24, 0)

  // ---- per-channel sum/sumsq from registers (rows < 250 only)
  float s1v[4] = {0.f, 0.f, 0.f, 0.f}, s2v[4] = {0.f, 0.f, 0.f, 0.f};
#pragma unroll
  for (int rt = 0; rt < 4; ++rt) {
#pragma unroll
    for (int qq = 0; qq < 4; ++qq) {
      int rloc = (wid << 6) + (rt << 4) + (lk << 2) + qq;  // C/D row
      if (rloc < RPB_) {
#pragma unroll
        for (int ct = 0; ct < 4; ++ct) {
          float val = acc[rt][ct][qq];
          s1v[ct] += val;
          s2v[ct] += val * val;
        }
      }
    }
  }
#pragma unroll
  for (int ct = 0; ct < 4; ++ct) {
    float a = s1v[ct], b = s2v[ct];
    a += __shfl_xor(a, 16); a += __shfl_xor(a, 32);
    b += __shfl_xor(b, 16); b += __shfl_xor(b, 32);
    if (lane < 16) {
      int base = ((((wid << 2) + ct) << 4) + l15) * 2;
      red2[base]     = a;
      red2[base + 1] = b;
    }
  }

  // ---- epilogue: 4 o-quarters via LDS transpose, coalesced float2 stores
  float* T = (float*)Ash;
  float* outb = out + n * 480000 + r0;     // + o*7500 + row
#pragma unroll
  for (int qt = 0; qt < 4; ++qt) {
    __syncthreads();   // qt=0: K-loop LDS reads + red2 writes done; else T reads
#pragma unroll
    for (int rt = 0; rt < 4; ++rt) {
      int row0 = (wid << 6) + (rt << 4) + (lk << 2);
      *(f32x4*)&T[l15 * TS_ + row0] = acc[rt][qt];
    }
    __syncthreads();
    if (qt == 0 && tid < 128) {   // deterministic partial reduction
      int o = tid >> 1, m = tid & 1;
      int ct = o >> 4, ol = o & 15;
      float sres = 0.f;
#pragma unroll
      for (int w = 0; w < 4; ++w)
        sres += red2[((((w << 2) + ct) << 4) + ol) * 2 + m];
      int bl = n * NBR_ + br;
      partials[bl * 128 + m * 64 + o] = sres;
    }
    // stores: 16 o x 125 float2 rows (250 rows, 8B aligned for any br)
#pragma unroll
    for (int it = 0; it < 8; ++it) {
      int idx = tid + it * NTHR_;
      if (idx < 2000) {
        int ol = idx / 125, r2 = idx - ol * 125;
        *(float2*)&outb[((qt << 4) + ol) * 7500 + (r2 << 1)] =
            *(float2*)&T[ol * TS_ + (r2 << 1)];
      }
    }
  }
}

// --- P2: reduce per-block partials -> per-channel scale/shift --------------
__global__ void finalize_kernel(const float* __restrict__ part,
                                const float* __restrict__ gamma,
                                const float* __restrict__ beta,
                                float* __restrict__ scsh) {
  __shared__ float sm[512];
  int o = blockIdx.x;            // 64 blocks, one channel each
  int tid = threadIdx.x;         // 256 threads
  float s1 = 0.f, s2 = 0.f;
  for (int b = tid; b < 64 * NBR_; b += 256) {
    s1 += part[b * 128 + o];
    s2 += part[b * 128 + 64 + o];
  }
  sm[tid] = s1; sm[256 + tid] = s2;
  __syncthreads();
  for (int st = 128; st >= 1; st >>= 1) {
    if (tid < st) { sm[tid] += sm[tid + st]; sm[256 + tid] += sm[256 + tid + st]; }
    __syncthreads();
  }
  if (tid == 0) {
    const float inv = 1.0f / 480000.0f;
    float mean = sm[0] * inv;
    float var  = sm[256] * inv - mean * mean;
    float sc = gamma[o] * rsqrtf(var + 1e-5f);
    float sh = beta[o] - mean * sc;
    scsh[o]      = sc;
    scsh[64 + o] = sh;
  }
}

// --- P3: in-place BN-apply + ReLU, float4 ----------------------------------
__global__ void bn_relu_kernel(float4* __restrict__ out, const float* __restrict__ scsh) {
  int i = blockIdx.x * blockDim.x + threadIdx.x;
  const int total = 7680000;        // 30.72M / 4 ; 7500%4==0 so o uniform per f4
  int stride = gridDim.x * blockDim.x;
  for (; i < total; i += stride) {
    int o = (i / 1875) & 63;
    float sc = scsh[o], sh = scsh[64 + o];
    float4 v = out[i];
    v.x = fmaxf(fmaf(v.x, sc, sh), 0.f);
    v.y = fmaxf(fmaf(v.y, sc, sh), 0.f);
    v.z = fmaxf(fmaf(v.z, sc, sh), 0.f);
    v.w = fmaxf(fmaf(v.w, sc, sh), 0.f);
    out[i] = v;
  }
}

// ---------------------------------------------------------------------------
extern "C" void kernel_launch(void* const* d_in, const int* in_sizes, int n_in,
                              void* d_out, int out_size, void* d_ws, size_t ws_size,
                              hipStream_t stream) {
  const float* x     = (const float*)d_in[0];
  const float* W     = (const float*)d_in[1];
  // d_in[2] = b : cancels under batch-norm, unused.
  const float* gamma = (const float*)d_in[3];
  const float* beta  = (const float*)d_in[4];
  float* out = (float*)d_out;

  char* ws = (char*)d_ws;
  s16x8* Wg       = (s16x8*)ws;                       // 204,800 B
  float* partials = (float*)(ws + 204800);            // 1920*128*4 = 983,040 B
  float* scsh     = (float*)(ws + 204800 + 983040);   // 512 B

  pack_w_kernel<<<dim3(50), dim3(256), 0, stream>>>(W, Wg);
  tap_mm_kernel<<<dim3(NBR_, 64), dim3(NTHR_), 0, stream>>>(x, Wg, out, partials);
  finalize_kernel<<<dim3(64), dim3(256), 0, stream>>>(partials, gamma, beta, scsh);
  bn_relu_kernel<<<dim3(2048), dim3(256), 0, stream>>>((float4*)out, scsh);
}

// Round 14
// 179.326 us; speedup vs baseline: 1.3053x; 1.0083x over previous
//
#include <hip/hip_runtime.h>

// ---------------------------------------------------------------------------
// unit_gcn: out[n,o,t,v] = BN+ReLU of  sum_{s=0..24} Ws[s] @_c x[n,:,t,(v+s)%25]
//   Ws[0] = sum_i W[i,:,:,0];  Ws[s] = W[s-1,:,:,1]  (s>=1); bias cancels in BN.
// N=64, C=64, T=300, V=25, O=64.  x fp32 -> bf16 MFMA (16x16x32), fp32 accum.
// v11 (R14): counted-vmcnt schedule (T3/T4): B staged via global_load_lds into
// a 3x8KB ring, loads issued 2 shifts ahead and NEVER drained to 0 in-loop;
// raw s_barrier + asm vmcnt(2) once per shift; A-slab transposed (R13).
// ---------------------------------------------------------------------------

typedef short  s16x8 __attribute__((ext_vector_type(8)));
typedef float  f32x4 __attribute__((ext_vector_type(4)));

#define NTHR_   256
#define RPB_    250         // rows per block (exactly 10 t x 25 v)
#define NBR_    30          // 7500 / 250
#define TS_     260         // epilogue transpose stride (f32)

__device__ __forceinline__ unsigned short f2bf(float f) {
  unsigned u = __builtin_bit_cast(unsigned, f);
  return (unsigned short)((u + 0x7FFFu + ((u >> 16) & 1u)) >> 16);
}

// global -> LDS direct DMA, 16B per lane (dst = wave-uniform base + lane*16)
#define GLDS16(G, L)                                                           \
  __builtin_amdgcn_global_load_lds(                                            \
      (const __attribute__((address_space(1))) void*)(G),                      \
      (__attribute__((address_space(3))) void*)(L), 16, 0, 0);

// --- P0: pack Ws into MFMA B-fragment layout (s-major: q = s*2 + chunk) ----
// Wg entry idx = ((s*2+chunk)*4 + ni)*64 + lane ; 8 bf16 per entry:
//   elem j = Ws[s][ o = ni*16 + (lane&15) ][ c = chunk*32 + (lane>>4)*8 + j ]
__global__ void pack_w_kernel(const float* __restrict__ W, s16x8* __restrict__ Wg) {
  int idx = blockIdx.x * 256 + threadIdx.x;
  if (idx >= 12800) return;
  int lane  = idx & 63;
  int ni    = (idx >> 6) & 3;
  int chunk = (idx >> 8) & 1;
  int s     = idx >> 9;
  int o     = (ni << 4) + (lane & 15);
  int cbase = (chunk << 5) + ((lane >> 4) << 3);
  s16x8 h;
#pragma unroll
  for (int j = 0; j < 8; ++j) {
    int c = cbase + j;
    float val;
    if (s == 0) {
      val = 0.f;
      for (int i = 0; i < 24; ++i) val += W[((i * 64 + o) * 64 + c) * 2];
    } else {
      val = W[(((s - 1) * 64 + o) * 64 + c) * 2 + 1];
    }
    h[j] = (short)f2bf(val);
  }
  Wg[idx] = h;
}

// advance row-tile J's shift state (period 25); aoc is byte offset into Ash
#define ADV(J) { bool w_ = (u[J] == 24); u[J] = w_ ? 0 : u[J] + 1; \
                 aoc[J] += w_ ? -384 : 16; }
// one MFMA
#define MM(RT, CT, AF, BF) \
  acc[RT][CT] = __builtin_amdgcn_mfma_f32_16x16x32_bf16(AF, BF, acc[RT][CT], 0, 0, 0);

// One shift s. Buffers (literals): CUR holds B(s), NXT holds B(s+1), FUT gets
// B(s+2) via global_load_lds issued NOW (in flight across the barrier; only
// wait is vmcnt(2) which leaves this pair flying while ensuring B(s+1) landed).
// PH_A: 16 MFMA ch0 + read Aq (ch1, Ash+16384) and Bq (ch1 from CUR).
// asm vmcnt(2); raw s_barrier; sched_barrier. PH_B: 16 MFMA ch1 + read
// Ap/Bp for s+1 (B from NXT). No ds_writes, no vmcnt(0) anywhere in-loop.
#define SHIFT(S_, CUR, NXT, FUT)                                               \
  {                                                                            \
    int sq_ = (S_) + 2; sq_ = (sq_ > 24) ? 24 : sq_;                           \
    const char* g_ = (const char*)(Wg + sq_ * 512) + goff;                     \
    GLDS16(g_,        Bsh + (FUT) * 8192 + loff)                               \
    GLDS16(g_ + 1024, Bsh + (FUT) * 8192 + loff + 1024)                        \
    const char* bq_ = Bsh + (CUR) * 8192 + 4096 + (lane << 4);                 \
    __builtin_amdgcn_s_setprio(1);                                             \
    Aq0 = *(const s16x8*)(Ash + aoc[0] + 16384);                               \
    MM(0, 0, Ap0, Bp0) MM(0, 1, Ap0, Bp1)                                      \
    Bq0 = *(const s16x8*)(bq_);                                                \
    MM(0, 2, Ap0, Bp2) MM(0, 3, Ap0, Bp3)                                      \
    Aq1 = *(const s16x8*)(Ash + aoc[1] + 16384);                               \
    MM(1, 0, Ap1, Bp0) MM(1, 1, Ap1, Bp1)                                      \
    Bq1 = *(const s16x8*)(bq_ + 1024);                                         \
    MM(1, 2, Ap1, Bp2) MM(1, 3, Ap1, Bp3)                                      \
    Aq2 = *(const s16x8*)(Ash + aoc[2] + 16384);                               \
    MM(2, 0, Ap2, Bp0) MM(2, 1, Ap2, Bp1)                                      \
    Bq2 = *(const s16x8*)(bq_ + 2048);                                         \
    MM(2, 2, Ap2, Bp2) MM(2, 3, Ap2, Bp3)                                      \
    Aq3 = *(const s16x8*)(Ash + aoc[3] + 16384);                               \
    MM(3, 0, Ap3, Bp0) MM(3, 1, Ap3, Bp1)                                      \
    Bq3 = *(const s16x8*)(bq_ + 3072);                                         \
    MM(3, 2, Ap3, Bp2) MM(3, 3, Ap3, Bp3)                                      \
    __builtin_amdgcn_s_setprio(0);                                             \
    asm volatile("s_waitcnt vmcnt(2)" ::: "memory");                           \
    __builtin_amdgcn_s_barrier();                                              \
    __builtin_amdgcn_sched_barrier(0);                                         \
    const char* bp_ = Bsh + (NXT) * 8192 + (lane << 4);                        \
    __builtin_amdgcn_s_setprio(1);                                             \
    ADV(0) Ap0 = *(const s16x8*)(Ash + aoc[0]);                                \
    MM(0, 0, Aq0, Bq0) MM(0, 1, Aq0, Bq1)                                      \
    Bp0 = *(const s16x8*)(bp_);                                                \
    MM(0, 2, Aq0, Bq2) MM(0, 3, Aq0, Bq3)                                      \
    ADV(1) Ap1 = *(const s16x8*)(Ash + aoc[1]);                                \
    MM(1, 0, Aq1, Bq0) MM(1, 1, Aq1, Bq1)                                      \
    Bp1 = *(const s16x8*)(bp_ + 1024);                                         \
    MM(1, 2, Aq1, Bq2) MM(1, 3, Aq1, Bq3)                                      \
    ADV(2) Ap2 = *(const s16x8*)(Ash + aoc[2]);                                \
    MM(2, 0, Aq2, Bq0) MM(2, 1, Aq2, Bq1)                                      \
    Bp2 = *(const s16x8*)(bp_ + 2048);                                         \
    MM(2, 2, Aq2, Bq2) MM(2, 3, Aq2, Bq3)                                      \
    ADV(3) Ap3 = *(const s16x8*)(Ash + aoc[3]);                                \
    MM(3, 0, Aq3, Bq0) MM(3, 1, Aq3, Bq1)                                      \
    Bp3 = *(const s16x8*)(bp_ + 3072);                                         \
    MM(3, 2, Aq3, Bq2) MM(3, 3, Aq3, Bq3)                                      \
    __builtin_amdgcn_s_setprio(0);                                             \
  }

// --- P1: main tap-GEMM -----------------------------------------------------
// grid (br=30, n=64), 256 thr = 4 waves; wave owns 64 rows x 64 o.
// A-slab TRANSPOSED: A_T[slot 0..7][row 0..255] 16B frags (slot = c-group);
// frag(row, ch) for lane: addr = (ch*4 + lk)*4096 + row*16.
__global__ __launch_bounds__(NTHR_) void tap_mm_kernel(
    const float* __restrict__ x, const s16x8* __restrict__ Wg,
    float* __restrict__ out, float* __restrict__ partials) {
  __shared__ __align__(16) char Ash[32768];   // A_T 8x256x16B; epi T[16][260]
  __shared__ __align__(16) char Bsh[24576];   // B ring: 3 x 8KB
  __shared__ float red2[512];
  int br = blockIdx.x, n = blockIdx.y;
  int r0 = br * RPB_;                 // 25-aligned
  const float* xn = x + n * 480000 + r0;
  int tid = threadIdx.x;
  int wid = tid >> 6, lane = tid & 63;
  int l15 = lane & 15, lk = lane >> 4;
  int goff = (wid << 11) + (lane << 4);   // byte offset within an 8KB B-block
  int loff = (wid << 11);                 // wave-uniform LDS offset

  // ---- prologue: B(0)->buf0, B(1)->buf1 via global_load_lds (fly under A-stage)
  {
    const char* g0 = (const char*)Wg + goff;
    GLDS16(g0,        Bsh + loff)
    GLDS16(g0 + 1024, Bsh + loff + 1024)
    const char* g1 = (const char*)(Wg + 512) + goff;
    GLDS16(g1,        Bsh + 8192 + loff)
    GLDS16(g1 + 1024, Bsh + 8192 + loff + 1024)
  }

  // ---- stage A_T: iteration it = slot; row = tid (250..255 zero pad)
#pragma unroll 2
  for (int it = 0; it < 8; ++it) {
    bool vld = tid < RPB_;
    s16x8 h;
#pragma unroll
    for (int j = 0; j < 8; ++j) {
      float f = vld ? xn[((it << 3) + j) * 7500 + tid] : 0.f;
      h[j] = (short)f2bf(f);
    }
    *(s16x8*)(Ash + (it << 12) + (tid << 4)) = h;
  }

  // ---- per-lane A row state: aoc = lk*4096 + srow*16 (ch0 byte offset)
  int u[4], aoc[4];
#pragma unroll
  for (int rt = 0; rt < 4; ++rt) {
    int srow = (wid << 6) + (rt << 4) + l15;     // local slab row (A-side)
    u[rt]   = srow % 25;                         // r0 is 25-aligned
    aoc[rt] = (lk << 12) + (srow << 4);
  }
  f32x4 acc[4][4];
#pragma unroll
  for (int rt = 0; rt < 4; ++rt)
#pragma unroll
    for (int ct = 0; ct < 4; ++ct) acc[rt][ct] = (f32x4){0.f, 0.f, 0.f, 0.f};

  __syncthreads();   // prologue-only full drain: A-slab + B(0),B(1) ready

  // ---- preload ch0 frags of shift 0
  s16x8 Ap0 = *(const s16x8*)(Ash + aoc[0]);
  s16x8 Ap1 = *(const s16x8*)(Ash + aoc[1]);
  s16x8 Ap2 = *(const s16x8*)(Ash + aoc[2]);
  s16x8 Ap3 = *(const s16x8*)(Ash + aoc[3]);
  const char* b0_ = Bsh + (lane << 4);
  s16x8 Bp0 = *(const s16x8*)(b0_);
  s16x8 Bp1 = *(const s16x8*)(b0_ + 1024);
  s16x8 Bp2 = *(const s16x8*)(b0_ + 2048);
  s16x8 Bp3 = *(const s16x8*)(b0_ + 3072);
  s16x8 Aq0, Aq1, Aq2, Aq3, Bq0, Bq1, Bq2, Bq3;

  // ---- 25 shifts; buffer role rotation has period 3 (6-shift unrolled body)
  for (int base = 0; base < 24; base += 6) {
    SHIFT(base + 0, 0, 1, 2)
    SHIFT(base + 1, 1, 2, 0)
    SHIFT(base + 2, 2, 0, 1)
    SHIFT(base + 3, 0, 1, 2)
    SHIFT(base + 4, 1, 2, 0)
    SHIFT(base + 5, 2, 0, 1)
  }
  SHIFT(24, 0, 1, 2)

  // ---- per-channel sum/sumsq from registers (rows < 250 only)
  float s1v[4] = {0.f, 0.f, 0.f, 0.f}, s2v[4] = {0.f, 0.f, 0.f, 0.f};
#pragma unroll
  for (int rt = 0; rt < 4; ++rt) {
#pragma unroll
    for (int qq = 0; qq < 4; ++qq) {
      int rloc = (wid << 6) + (rt << 4) + (lk << 2) + qq;  // C/D row
      if (rloc < RPB_) {
#pragma unroll
        for (int ct = 0; ct < 4; ++ct) {
          float val = acc[rt][ct][qq];
          s1v[ct] += val;
          s2v[ct] += val * val;
        }
      }
    }
  }
#pragma unroll
  for (int ct = 0; ct < 4; ++ct) {
    float a = s1v[ct], b = s2v[ct];
    a += __shfl_xor(a, 16); a += __shfl_xor(a, 32);
    b += __shfl_xor(b, 16); b += __shfl_xor(b, 32);
    if (lane < 16) {
      int base = ((((wid << 2) + ct) << 4) + l15) * 2;
      red2[base]     = a;
      red2[base + 1] = b;
    }
  }

  // ---- epilogue: 4 o-quarters via LDS transpose, coalesced float2 stores
  float* T = (float*)Ash;
  float* outb = out + n * 480000 + r0;     // + o*7500 + row
#pragma unroll
  for (int qt = 0; qt < 4; ++qt) {
    __syncthreads();   // full drain: K-loop LDS reads + stray gl_lds done
#pragma unroll
    for (int rt = 0; rt < 4; ++rt) {
      int row0 = (wid << 6) + (rt << 4) + (lk << 2);
      *(f32x4*)&T[l15 * TS_ + row0] = acc[rt][qt];
    }
    __syncthreads();
    if (qt == 0 && tid < 128) {   // deterministic partial reduction
      int o = tid >> 1, m = tid & 1;
      int ct = o >> 4, ol = o & 15;
      float sres = 0.f;
#pragma unroll
      for (int w = 0; w < 4; ++w)
        sres += red2[((((w << 2) + ct) << 4) + ol) * 2 + m];
      int bl = n * NBR_ + br;
      partials[bl * 128 + m * 64 + o] = sres;
    }
    // stores: 16 o x 125 float2 rows (250 rows, 8B aligned for any br)
#pragma unroll
    for (int it = 0; it < 8; ++it) {
      int idx = tid + it * NTHR_;
      if (idx < 2000) {
        int ol = idx / 125, r2 = idx - ol * 125;
        *(float2*)&outb[((qt << 4) + ol) * 7500 + (r2 << 1)] =
            *(float2*)&T[ol * TS_ + (r2 << 1)];
      }
    }
  }
}

// --- P2: reduce per-block partials -> per-channel scale/shift --------------
__global__ void finalize_kernel(const float* __restrict__ part,
                                const float* __restrict__ gamma,
                                const float* __restrict__ beta,
                                float* __restrict__ scsh) {
  __shared__ float sm[512];
  int o = blockIdx.x;            // 64 blocks, one channel each
  int tid = threadIdx.x;         // 256 threads
  float s1 = 0.f, s2 = 0.f;
  for (int b = tid; b < 64 * NBR_; b += 256) {
    s1 += part[b * 128 + o];
    s2 += part[b * 128 + 64 + o];
  }
  sm[tid] = s1; sm[256 + tid] = s2;
  __syncthreads();
  for (int st = 128; st >= 1; st >>= 1) {
    if (tid < st) { sm[tid] += sm[tid + st]; sm[256 + tid] += sm[256 + tid + st]; }
    __syncthreads();
  }
  if (tid == 0) {
    const float inv = 1.0f / 480000.0f;
    float mean = sm[0] * inv;
    float var  = sm[256] * inv - mean * mean;
    float sc = gamma[o] * rsqrtf(var + 1e-5f);
    float sh = beta[o] - mean * sc;
    scsh[o]      = sc;
    scsh[64 + o] = sh;
  }
}

// --- P3: in-place BN-apply + ReLU, float4 ----------------------------------
__global__ void bn_relu_kernel(float4* __restrict__ out, const float* __restrict__ scsh) {
  int i = blockIdx.x * blockDim.x + threadIdx.x;
  const int total = 7680000;        // 30.72M / 4 ; 7500%4==0 so o uniform per f4
  int stride = gridDim.x * blockDim.x;
  for (; i < total; i += stride) {
    int o = (i / 1875) & 63;
    float sc = scsh[o], sh = scsh[64 + o];
    float4 v = out[i];
    v.x = fmaxf(fmaf(v.x, sc, sh), 0.f);
    v.y = fmaxf(fmaf(v.y, sc, sh), 0.f);
    v.z = fmaxf(fmaf(v.z, sc, sh), 0.f);
    v.w = fmaxf(fmaf(v.w, sc, sh), 0.f);
    out[i] = v;
  }
}

// ---------------------------------------------------------------------------
extern "C" void kernel_launch(void* const* d_in, const int* in_sizes, int n_in,
                              void* d_out, int out_size, void* d_ws, size_t ws_size,
                              hipStream_t stream) {
  const float* x     = (const float*)d_in[0];
  const float* W     = (const float*)d_in[1];
  // d_in[2] = b : cancels under batch-norm, unused.
  const float* gamma = (const float*)d_in[3];
  const float* beta  = (const float*)d_in[4];
  float* out = (float*)d_out;

  char* ws = (char*)d_ws;
  s16x8* Wg       = (s16x8*)ws;                       // 204,800 B
  float* partials = (float*)(ws + 204800);            // 1920*128*4 = 983,040 B
  float* scsh     = (float*)(ws + 204800 + 983040);   // 512 B

  pack_w_kernel<<<dim3(50), dim3(256), 0, stream>>>(W, Wg);
  tap_mm_kernel<<<dim3(NBR_, 64), dim3(NTHR_), 0, stream>>>(x, Wg, out, partials);
  finalize_kernel<<<dim3(64), dim3(256), 0, stream>>>(partials, gamma, beta, scsh);
  bn_relu_kernel<<<dim3(2048), dim3(256), 0, stream>>>((float4*)out, scsh);
}